// Round 3
// baseline (828.835 us; speedup 1.0000x reference)
//
#include <hip/hip_runtime.h>

using u32 = unsigned int;
using s64 = long long;

// -------- int width detection (int64 iff hi-words of first 64 entries all 0) --------
__global__ __launch_bounds__(64) void k_detect13(const u32* __restrict__ ei,
                                                 const u32* __restrict__ nt,
                                                 const u32* __restrict__ tp,
                                                 u32* __restrict__ flags) {
    if (blockIdx.x != 0 || threadIdx.x != 0) return;
    bool e64 = true, n64 = true, t64 = true;
    for (int k = 0; k < 64; ++k) {
        if (ei[2 * k + 1] != 0u) e64 = false;
        if (nt[2 * k + 1] != 0u) n64 = false;
        if (tp[2 * k + 1] != 0u) t64 = false;
    }
    flags[0] = e64 ? 1u : 0u;
    flags[1] = n64 ? 1u : 0u;
    flags[2] = t64 ? 1u : 0u;
}

// -------- width-adaptive convert to int32 --------
__global__ __launch_bounds__(256) void k_cvt13(const void* __restrict__ src,
                                               int* __restrict__ dst, long long n,
                                               const u32* __restrict__ flags, int fidx) {
    long long i = (long long)blockIdx.x * 256 + threadIdx.x;
    if (i >= n) return;
    dst[i] = flags[fidx] ? (int)((const s64*)src)[i] : ((const int*)src)[i];
}

// ---------------- zero (float / int) ----------------
__global__ __launch_bounds__(256) void kz13(float* __restrict__ p, long long n) {
    long long i = (long long)blockIdx.x * 256 + threadIdx.x;
    if (i < n) p[i] = 0.f;
}
__global__ __launch_bounds__(256) void kz_i(int* __restrict__ p, int n) {
    int i = blockIdx.x * 256 + threadIdx.x;
    if (i < n) p[i] = 0;
}

// ---------------- counting sort of edges by col ----------------
__global__ __launch_bounds__(256) void k_hist(const int* __restrict__ ei, int E,
                                              int* __restrict__ cnt) {
    int e = blockIdx.x * 256 + threadIdx.x;
    if (e < E) atomicAdd(&cnt[ei[E + e]], 1);
}

__global__ __launch_bounds__(1024) void k_scan(const int* __restrict__ cnt,
                                               int* __restrict__ offA, int N) {
    __shared__ int part[1024];
    int t = threadIdx.x;
    int C = (N + 1023) >> 10;
    int beg = t * C, end = beg + C; if (end > N) end = N;
    int s = 0;
    for (int k = beg; k < end; ++k) s += cnt[k];
    part[t] = s; __syncthreads();
    for (int o = 1; o < 1024; o <<= 1) {
        int v = (t >= o) ? part[t - o] : 0;
        __syncthreads();
        part[t] += v;
        __syncthreads();
    }
    int base = (t == 0) ? 0 : part[t - 1];
    for (int k = beg; k < end; ++k) { offA[k] = base; base += cnt[k]; }
    if (t == 1023) offA[N] = part[1023];
}

__global__ __launch_bounds__(256) void k_scatter(const int* __restrict__ ei, int E,
                                                 const int* __restrict__ offA,
                                                 int* __restrict__ cur,
                                                 int* __restrict__ srow,
                                                 int* __restrict__ sedge) {
    int e = blockIdx.x * 256 + threadIdx.x;
    if (e >= E) return;
    int col = ei[E + e];
    int p = offA[col] + atomicAdd(&cur[col], 1);
    srow[p] = ei[e];
    sedge[p] = e;
}

// ---------------- counting sort of nodes by type (6 bins) ----------------
__global__ __launch_bounds__(256) void k_thist(const int* __restrict__ nt, int N,
                                               int* __restrict__ tcnt) {
    __shared__ int lc[6];
    if (threadIdx.x < 6) lc[threadIdx.x] = 0;
    __syncthreads();
    int i = blockIdx.x * 256 + threadIdx.x;
    if (i < N) {
        int t = nt[i]; t = (t < 0 || t > 5) ? 0 : t;
        atomicAdd(&lc[t], 1);
    }
    __syncthreads();
    if (threadIdx.x < 6 && lc[threadIdx.x] > 0) atomicAdd(&tcnt[threadIdx.x], lc[threadIdx.x]);
}

__global__ __launch_bounds__(64) void k_tscan(const int* __restrict__ tcnt,
                                              int* __restrict__ toff) {
    if (threadIdx.x != 0 || blockIdx.x != 0) return;
    int s = 0;
    for (int t = 0; t < 6; ++t) { toff[t] = s; s += tcnt[t]; }
    toff[6] = s;
}

__global__ __launch_bounds__(256) void k_tscatter(const int* __restrict__ nt, int N,
                                                  const int* __restrict__ toff,
                                                  int* __restrict__ tcur,
                                                  int* __restrict__ perm) {
    __shared__ int lc[6], gb[6];
    if (threadIdx.x < 6) lc[threadIdx.x] = 0;
    __syncthreads();
    int i = blockIdx.x * 256 + threadIdx.x;
    int t = 0, lr = 0;
    if (i < N) {
        t = nt[i]; t = (t < 0 || t > 5) ? 0 : t;
        lr = atomicAdd(&lc[t], 1);
    }
    __syncthreads();
    if (threadIdx.x < 6 && lc[threadIdx.x] > 0)
        gb[threadIdx.x] = atomicAdd(&tcur[threadIdx.x], lc[threadIdx.x]);
    __syncthreads();
    if (i < N) perm[toff[t] + gb[t] + lr] = i;
}

// wave-wide sum over 64 lanes
__device__ __forceinline__ float wredsum(float v) {
#pragma unroll
    for (int o = 32; o; o >>= 1) v += __shfl_xor(v, o);
    return v;
}

__device__ __forceinline__ float2 ld2(const float* p) { return *(const float2*)p; }
__device__ __forceinline__ void st2(float* p, float2 v) { *(float2*)p = v; }

// acc += a @ W  (W row-major 128x128); lane l owns cols 2l, 2l+1; 8 nodes/wave
__device__ __forceinline__ void mm8(const float2 (&a)[8], float2 (&acc)[8],
                                    const float* __restrict__ W, int l) {
    const float2* Wf2 = (const float2*)W;
#pragma unroll 8
    for (int k2 = 0; k2 < 64; ++k2) {
        float2 wA = Wf2[(2 * k2) * 64 + l];
        float2 wB = Wf2[(2 * k2 + 1) * 64 + l];
#pragma unroll
        for (int n = 0; n < 8; ++n) {
            float x0 = __shfl(a[n].x, k2);
            float x1 = __shfl(a[n].y, k2);
            acc[n].x = fmaf(x0, wA.x, acc[n].x); acc[n].x = fmaf(x1, wB.x, acc[n].x);
            acc[n].y = fmaf(x0, wA.y, acc[n].y); acc[n].y = fmaf(x1, wB.y, acc[n].y);
        }
    }
}

// ---------------- QKV: 8 nodes/wave, 3 fused matmuls ----------------
__global__ __launch_bounds__(256) void k_qkv8(const float* __restrict__ x,
                                              const float* __restrict__ Wq,
                                              const float* __restrict__ Wk,
                                              const float* __restrict__ Wv,
                                              float* __restrict__ big, int N) {
    int l = threadIdx.x & 63;
    int i0 = (blockIdx.x * 4 + (threadIdx.x >> 6)) * 8;
    if (i0 >= N) return;
    int nn = N - i0; if (nn > 8) nn = 8;
    float2 a[8];
#pragma unroll
    for (int n = 0; n < 8; ++n) {
        int i = i0 + (n < nn ? n : 0);
        a[n] = ld2(x + (size_t)i * 128 + 2 * l);
    }
    float2 q[8], kk[8], v[8];
#pragma unroll
    for (int n = 0; n < 8; ++n) {
        q[n] = make_float2(0.f, 0.f); kk[n] = make_float2(0.f, 0.f); v[n] = make_float2(0.f, 0.f);
    }
    const float2* Wqf = (const float2*)Wq;
    const float2* Wkf = (const float2*)Wk;
    const float2* Wvf = (const float2*)Wv;
#pragma unroll 4
    for (int k2 = 0; k2 < 64; ++k2) {
        float2 wq0 = Wqf[(2 * k2) * 64 + l], wq1 = Wqf[(2 * k2 + 1) * 64 + l];
        float2 wk0 = Wkf[(2 * k2) * 64 + l], wk1 = Wkf[(2 * k2 + 1) * 64 + l];
        float2 wv0 = Wvf[(2 * k2) * 64 + l], wv1 = Wvf[(2 * k2 + 1) * 64 + l];
#pragma unroll
        for (int n = 0; n < 8; ++n) {
            float x0 = __shfl(a[n].x, k2);
            float x1 = __shfl(a[n].y, k2);
            q[n].x = fmaf(x0, wq0.x, q[n].x);  q[n].x = fmaf(x1, wq1.x, q[n].x);
            q[n].y = fmaf(x0, wq0.y, q[n].y);  q[n].y = fmaf(x1, wq1.y, q[n].y);
            kk[n].x = fmaf(x0, wk0.x, kk[n].x); kk[n].x = fmaf(x1, wk1.x, kk[n].x);
            kk[n].y = fmaf(x0, wk0.y, kk[n].y); kk[n].y = fmaf(x1, wk1.y, kk[n].y);
            v[n].x = fmaf(x0, wv0.x, v[n].x);  v[n].x = fmaf(x1, wv1.x, v[n].x);
            v[n].y = fmaf(x0, wv0.y, v[n].y);  v[n].y = fmaf(x1, wv1.y, v[n].y);
        }
    }
#pragma unroll
    for (int n = 0; n < 8; ++n) if (n < nn) {
        size_t b = (size_t)(i0 + n) * 384;
        st2(big + b + 2 * l, q[n]);
        st2(big + b + 128 + 2 * l, kk[n]);
        st2(big + b + 256 + 2 * l, v[n]);
    }
}

// ---------------- GAT scores (float4 gathers): exp + segment denominator ----------------
__global__ __launch_bounds__(256) void k_gat_smB(const float* __restrict__ big,
                                                 const int* __restrict__ ei, int E,
                                                 float* __restrict__ scores,
                                                 float* __restrict__ sm) {
    long long t = (long long)blockIdx.x * 256 + threadIdx.x;
    if (t >= (long long)E * 8) return;
    int e = (int)(t >> 3), h = (int)(t & 7);
    int row = ei[e], col = ei[E + e];
    const float4* q = (const float4*)(big + (size_t)row * 384 + h * 16);
    const float4* kk = (const float4*)(big + (size_t)col * 384 + 128 + h * 16);
    float s = 0.f;
#pragma unroll
    for (int d = 0; d < 4; ++d) {
        float4 a = q[d], b = kk[d];
        s += a.x * b.x + a.y * b.y + a.z * b.z + a.w * b.w;
    }
    s *= 0.25f;
    s = s > 0.f ? s : 0.2f * s;
    float ex = expf(s);
    scores[t] = ex;
    atomicAdd(&sm[(size_t)col * 8 + h], ex);
}

// ------- GAT weighted-V, sorted segments: one wave per col, float2 lanes -------
__global__ __launch_bounds__(256) void k_wvS2(const float* __restrict__ big,
                                              const float* __restrict__ scores,
                                              const float* __restrict__ sm,
                                              const int* __restrict__ srow,
                                              const int* __restrict__ sedge,
                                              const int* __restrict__ offA,
                                              float* __restrict__ agg, int N) {
    int l = threadIdx.x & 63;
    int col = blockIdx.x * 4 + (threadIdx.x >> 6);
    if (col >= N) return;
    int h = l >> 3;                      // cols 2l,2l+1 share head (2l)>>4 == l>>3
    float sv = sm[(size_t)col * 8 + h];
    float ism = sv != 0.f ? 1.f / sv : 0.f;
    float ax = 0.f, ay = 0.f;
    int p = offA[col], pe = offA[col + 1];
    for (; p + 2 <= pe; p += 2) {
        int e0 = sedge[p], r0 = srow[p], e1 = sedge[p + 1], r1 = srow[p + 1];
        float pr0 = scores[(size_t)e0 * 8 + h] * ism;
        float pr1 = scores[(size_t)e1 * 8 + h] * ism;
        float2 v0 = ld2(big + (size_t)r0 * 384 + 256 + 2 * l);
        float2 v1 = ld2(big + (size_t)r1 * 384 + 256 + 2 * l);
        ax = fmaf(pr0, v0.x, ax); ay = fmaf(pr0, v0.y, ay);
        ax = fmaf(pr1, v1.x, ax); ay = fmaf(pr1, v1.y, ay);
    }
    for (; p < pe; ++p) {
        int e = sedge[p], r = srow[p];
        float pr = scores[(size_t)e * 8 + h] * ism;
        float2 v = ld2(big + (size_t)r * 384 + 256 + 2 * l);
        ax = fmaf(pr, v.x, ax); ay = fmaf(pr, v.y, ay);
    }
    st2(agg + (size_t)col * 128 + 2 * l, make_float2(ax, ay));
}

// ---- GAT epilogue + fusion fold: fused = LN(agg@Wo+bo+x) @ fusW[0:128] + fus_b ----
__global__ __launch_bounds__(256) void k_ep_gatF8(const float* __restrict__ x,
                                                  const float* __restrict__ agg,
                                                  const float* __restrict__ Wo,
                                                  const float* __restrict__ bo,
                                                  const float* __restrict__ g,
                                                  const float* __restrict__ b,
                                                  const float* __restrict__ fusW,
                                                  const float* __restrict__ fus_b,
                                                  float* __restrict__ fused, int N) {
    int l = threadIdx.x & 63;
    int i0 = (blockIdx.x * 4 + (threadIdx.x >> 6)) * 8;
    if (i0 >= N) return;
    int nn = N - i0; if (nn > 8) nn = 8;
    float2 a[8], ac[8];
    float2 bo2 = ld2(bo + 2 * l);
#pragma unroll
    for (int n = 0; n < 8; ++n) {
        int i = i0 + (n < nn ? n : 0);
        a[n] = ld2(agg + (size_t)i * 128 + 2 * l);
        ac[n] = bo2;
    }
    mm8(a, ac, Wo, l);
    float2 g2 = ld2(g + 2 * l), b2 = ld2(b + 2 * l);
    float2 o[8];
#pragma unroll
    for (int n = 0; n < 8; ++n) {
        int i = i0 + (n < nn ? n : 0);
        float2 xr = ld2(x + (size_t)i * 128 + 2 * l);
        float v0 = ac[n].x + xr.x, v1 = ac[n].y + xr.y;
        float m = wredsum(v0 + v1) * 0.0078125f;
        float d0 = v0 - m, d1 = v1 - m;
        float r = rsqrtf(wredsum(d0 * d0 + d1 * d1) * 0.0078125f + 1e-5f);
        o[n].x = d0 * r * g2.x + b2.x;
        o[n].y = d1 * r * g2.y + b2.y;
    }
    float2 fb2 = ld2(fus_b + 2 * l);
    float2 ac2[8];
#pragma unroll
    for (int n = 0; n < 8; ++n) ac2[n] = fb2;
    mm8(o, ac2, fusW, l);
#pragma unroll
    for (int n = 0; n < 8; ++n) if (n < nn)
        st2(fused + (size_t)(i0 + n) * 128 + 2 * l, ac2[n]);
}

// ---------------- per-type transform, 8 nodes/wave, type-sorted ----------------
__global__ __launch_bounds__(256) void k_hgcn8(const float* __restrict__ x,
                                               const int* __restrict__ nt,
                                               const int* __restrict__ perm,
                                               const float* __restrict__ Wt,
                                               const float* __restrict__ bt,
                                               float* __restrict__ h_gcn, int N) {
    int l = threadIdx.x & 63;
    int i0 = (blockIdx.x * 4 + (threadIdx.x >> 6)) * 8;
    if (i0 >= N) return;
    int nn = N - i0; if (nn > 8) nn = 8;
    int idx[8], tt[8];
#pragma unroll
    for (int n = 0; n < 8; ++n) {
        idx[n] = perm[i0 + (n < nn ? n : 0)];
        int t = nt[idx[n]]; tt[n] = (t < 0 || t > 5) ? 0 : t;
    }
    bool same = true;
#pragma unroll
    for (int n = 1; n < 8; ++n) same = same && (tt[n] == tt[0]);
    float2 a[8], acc[8];
#pragma unroll
    for (int n = 0; n < 8; ++n) a[n] = ld2(x + (size_t)idx[n] * 128 + 2 * l);
    if (same) {
        float2 bt2 = ld2(bt + tt[0] * 128 + 2 * l);
#pragma unroll
        for (int n = 0; n < 8; ++n) acc[n] = bt2;
        mm8(a, acc, Wt + (size_t)tt[0] * 16384, l);
    } else {
        const float2* Wp[8];
#pragma unroll
        for (int n = 0; n < 8; ++n) {
            Wp[n] = (const float2*)(Wt + (size_t)tt[n] * 16384);
            acc[n] = ld2(bt + tt[n] * 128 + 2 * l);
        }
#pragma unroll 2
        for (int k2 = 0; k2 < 64; ++k2) {
#pragma unroll
            for (int n = 0; n < 8; ++n) {
                float2 wA = Wp[n][(2 * k2) * 64 + l];
                float2 wB = Wp[n][(2 * k2 + 1) * 64 + l];
                float x0 = __shfl(a[n].x, k2);
                float x1 = __shfl(a[n].y, k2);
                acc[n].x = fmaf(x0, wA.x, acc[n].x); acc[n].x = fmaf(x1, wB.x, acc[n].x);
                acc[n].y = fmaf(x0, wA.y, acc[n].y); acc[n].y = fmaf(x1, wB.y, acc[n].y);
            }
        }
    }
#pragma unroll
    for (int n = 0; n < 8; ++n) if (n < nn)
        st2(h_gcn + (size_t)idx[n] * 128 + 2 * l, acc[n]);
}

// ------- layer-1 precompute: Pa = h@W1[0:128], Pb = h@W1[128:256] + b1 -------
// mode 1: h = x + emb[clip(tpos)] computed inline
__global__ __launch_bounds__(256) void k_pre8(const float* __restrict__ h,
                                              const float* __restrict__ emb,
                                              const int* __restrict__ tpos,
                                              const float* __restrict__ W1,
                                              const float* __restrict__ b1,
                                              float* __restrict__ Pa,
                                              float* __restrict__ Pb, int N, int mode) {
    int l = threadIdx.x & 63;
    int i0 = (blockIdx.x * 4 + (threadIdx.x >> 6)) * 8;
    if (i0 >= N) return;
    int nn = N - i0; if (nn > 8) nn = 8;
    float2 a[8];
#pragma unroll
    for (int n = 0; n < 8; ++n) {
        int i = i0 + (n < nn ? n : 0);
        float2 v = ld2(h + (size_t)i * 128 + 2 * l);
        if (mode) {
            int tp = tpos[i]; tp = tp < 0 ? 0 : (tp > 49 ? 49 : tp);
            float2 e = ld2(emb + tp * 128 + 2 * l);
            v.x += e.x; v.y += e.y;
        }
        a[n] = v;
    }
    float2 b12 = ld2(b1 + 2 * l);
    float2 pa[8], pb[8];
#pragma unroll
    for (int n = 0; n < 8; ++n) { pa[n] = make_float2(0.f, 0.f); pb[n] = b12; }
    const float2* Wf = (const float2*)W1;
#pragma unroll 4
    for (int k2 = 0; k2 < 64; ++k2) {
        float2 wa0 = Wf[(2 * k2) * 64 + l],         wa1 = Wf[(2 * k2 + 1) * 64 + l];
        float2 wb0 = Wf[(128 + 2 * k2) * 64 + l],   wb1 = Wf[(128 + 2 * k2 + 1) * 64 + l];
#pragma unroll
        for (int n = 0; n < 8; ++n) {
            float x0 = __shfl(a[n].x, k2);
            float x1 = __shfl(a[n].y, k2);
            pa[n].x = fmaf(x0, wa0.x, pa[n].x); pa[n].x = fmaf(x1, wa1.x, pa[n].x);
            pa[n].y = fmaf(x0, wa0.y, pa[n].y); pa[n].y = fmaf(x1, wa1.y, pa[n].y);
            pb[n].x = fmaf(x0, wb0.x, pb[n].x); pb[n].x = fmaf(x1, wb1.x, pb[n].x);
            pb[n].y = fmaf(x0, wb0.y, pb[n].y); pb[n].y = fmaf(x1, wb1.y, pb[n].y);
        }
    }
#pragma unroll
    for (int n = 0; n < 8; ++n) if (n < nn) {
        size_t o = (size_t)(i0 + n) * 128;
        st2(Pa + o + 2 * l, pa[n]);
        st2(Pb + o + 2 * l, pb[n]);
    }
}

// ------- relu-sum over sorted segment: s[col] = sum_e relu(Pa[row_e]+Pb[col]) -------
__global__ __launch_bounds__(256) void k_rsum2(const float* __restrict__ Pa,
                                               const float* __restrict__ Pb,
                                               const int* __restrict__ srow,
                                               const int* __restrict__ offA,
                                               float* __restrict__ s, int N) {
    int l = threadIdx.x & 63;
    int col = blockIdx.x * 4 + (threadIdx.x >> 6);
    if (col >= N) return;
    float2 pb = ld2(Pb + (size_t)col * 128 + 2 * l);
    float ax = 0.f, ay = 0.f;
    int p = offA[col], pe = offA[col + 1];
    for (; p + 4 <= pe; p += 4) {
        int r0 = srow[p], r1 = srow[p + 1], r2 = srow[p + 2], r3 = srow[p + 3];
        float2 a0 = ld2(Pa + (size_t)r0 * 128 + 2 * l);
        float2 a1 = ld2(Pa + (size_t)r1 * 128 + 2 * l);
        float2 a2 = ld2(Pa + (size_t)r2 * 128 + 2 * l);
        float2 a3 = ld2(Pa + (size_t)r3 * 128 + 2 * l);
        ax += fmaxf(a0.x + pb.x, 0.f) + fmaxf(a1.x + pb.x, 0.f)
            + fmaxf(a2.x + pb.x, 0.f) + fmaxf(a3.x + pb.x, 0.f);
        ay += fmaxf(a0.y + pb.y, 0.f) + fmaxf(a1.y + pb.y, 0.f)
            + fmaxf(a2.y + pb.y, 0.f) + fmaxf(a3.y + pb.y, 0.f);
    }
    for (; p < pe; ++p) {
        int r = srow[p];
        float2 a = ld2(Pa + (size_t)r * 128 + 2 * l);
        ax += fmaxf(a.x + pb.x, 0.f);
        ay += fmaxf(a.y + pb.y, 0.f);
    }
    st2(s + (size_t)col * 128 + 2 * l, make_float2(ax, ay));
}

// ---- GCN epilogue + W2 fold + fusion fold (5 chained matmuls), 8 nodes/wave ----
__global__ __launch_bounds__(256) void k_ep_gcnF8(const float* __restrict__ x,
                                                  const float* __restrict__ h_gcn,
                                                  const float* __restrict__ s,
                                                  const int* __restrict__ offA,
                                                  const float* __restrict__ W2,
                                                  const float* __restrict__ b2,
                                                  const float* __restrict__ aW1,
                                                  const float* __restrict__ ab1,
                                                  const float* __restrict__ aW2,
                                                  const float* __restrict__ ab2,
                                                  const float* __restrict__ Wo,
                                                  const float* __restrict__ bo,
                                                  const float* __restrict__ g,
                                                  const float* __restrict__ b,
                                                  const float* __restrict__ fusW,
                                                  float* __restrict__ fused, int N) {
    int l = threadIdx.x & 63;
    int i0 = (blockIdx.x * 4 + (threadIdx.x >> 6)) * 8;
    if (i0 >= N) return;
    int nn = N - i0; if (nn > 8) nn = 8;
    float2 zr[8], t1[8];
    float2 b22 = ld2(b2 + 2 * l);
#pragma unroll
    for (int n = 0; n < 8; ++n) {
        int i = i0 + (n < nn ? n : 0);
        zr[n] = ld2(s + (size_t)i * 128 + 2 * l);
        float deg = (float)(offA[i + 1] - offA[i]);
        t1[n].x = deg * b22.x; t1[n].y = deg * b22.y;
    }
    mm8(zr, t1, W2, l);                       // t1 = agg = s@W2 + deg*b2
    float2 u[8];
    float2 a12 = ld2(ab1 + 2 * l);
#pragma unroll
    for (int n = 0; n < 8; ++n) u[n] = a12;
    mm8(t1, u, aW1, l);
#pragma unroll
    for (int n = 0; n < 8; ++n) {
        u[n].x = fmaxf(u[n].x, 0.f);
        u[n].y = fmaxf(u[n].y, 0.f);
    }
    float2 z3[8];
    float2 a22 = ld2(ab2 + 2 * l);
#pragma unroll
    for (int n = 0; n < 8; ++n) z3[n] = a22;
    mm8(u, z3, aW2, l);
#pragma unroll
    for (int n = 0; n < 8; ++n) {
        int i = i0 + (n < nn ? n : 0);
        float2 hg = ld2(h_gcn + (size_t)i * 128 + 2 * l);
        z3[n].x += hg.x; z3[n].y += hg.y;
    }
    float2 d[8];
    float2 bo2 = ld2(bo + 2 * l);
#pragma unroll
    for (int n = 0; n < 8; ++n) d[n] = bo2;
    mm8(z3, d, Wo, l);
    float2 g2 = ld2(g + 2 * l), bb2 = ld2(b + 2 * l);
    float2 o[8];
#pragma unroll
    for (int n = 0; n < 8; ++n) {
        int i = i0 + (n < nn ? n : 0);
        float2 xr = ld2(x + (size_t)i * 128 + 2 * l);
        float v0 = d[n].x + xr.x, v1 = d[n].y + xr.y;
        float m = wredsum(v0 + v1) * 0.0078125f;
        float d0 = v0 - m, d1 = v1 - m;
        float r = rsqrtf(wredsum(d0 * d0 + d1 * d1) * 0.0078125f + 1e-5f);
        o[n].x = d0 * r * g2.x + bb2.x;
        o[n].y = d1 * r * g2.y + bb2.y;
    }
    float2 ac2[8];
#pragma unroll
    for (int n = 0; n < 8; ++n) {
        int i = i0 + (n < nn ? n : 0);
        ac2[n] = ld2(fused + (size_t)i * 128 + 2 * l);
    }
    mm8(o, ac2, fusW + (size_t)128 * 128, l);
#pragma unroll
    for (int n = 0; n < 8; ++n) if (n < nn)
        st2(fused + (size_t)(i0 + n) * 128 + 2 * l, ac2[n]);
}

// ---- temporal epilogue + W2 fold + fusion fold + FINAL LN -> out ----
__global__ __launch_bounds__(256) void k_ep_tmpF8(const float* __restrict__ x,
                                                  const float* __restrict__ emb,
                                                  const int* __restrict__ tpos,
                                                  const float* __restrict__ s,
                                                  const int* __restrict__ offA,
                                                  const float* __restrict__ W2,
                                                  const float* __restrict__ b2,
                                                  const float* __restrict__ Wo,
                                                  const float* __restrict__ bo,
                                                  const float* __restrict__ g,
                                                  const float* __restrict__ b,
                                                  const float* __restrict__ fusW,
                                                  const float* __restrict__ fused,
                                                  const float* __restrict__ fg,
                                                  const float* __restrict__ fbe,
                                                  float* __restrict__ out, int N) {
    int l = threadIdx.x & 63;
    int i0 = (blockIdx.x * 4 + (threadIdx.x >> 6)) * 8;
    if (i0 >= N) return;
    int nn = N - i0; if (nn > 8) nn = 8;
    float2 zr[8], t1[8];
    float2 b22 = ld2(b2 + 2 * l);
#pragma unroll
    for (int n = 0; n < 8; ++n) {
        int i = i0 + (n < nn ? n : 0);
        zr[n] = ld2(s + (size_t)i * 128 + 2 * l);
        float deg = (float)(offA[i + 1] - offA[i]);
        t1[n].x = deg * b22.x; t1[n].y = deg * b22.y;
    }
    mm8(zr, t1, W2, l);                       // t1 = agg
    float2 z[8];
#pragma unroll
    for (int n = 0; n < 8; ++n) {
        int i = i0 + (n < nn ? n : 0);
        int tp = tpos[i]; tp = tp < 0 ? 0 : (tp > 49 ? 49 : tp);
        float2 xr = ld2(x + (size_t)i * 128 + 2 * l);
        float2 e = ld2(emb + tp * 128 + 2 * l);
        z[n].x = t1[n].x + xr.x + e.x;
        z[n].y = t1[n].y + xr.y + e.y;
    }
    float2 d[8];
    float2 bo2 = ld2(bo + 2 * l);
#pragma unroll
    for (int n = 0; n < 8; ++n) d[n] = bo2;
    mm8(z, d, Wo, l);
    float2 g2 = ld2(g + 2 * l), bb2 = ld2(b + 2 * l);
    float2 o[8];
#pragma unroll
    for (int n = 0; n < 8; ++n) {
        float v0 = d[n].x, v1 = d[n].y;
        float m = wredsum(v0 + v1) * 0.0078125f;
        float d0 = v0 - m, d1 = v1 - m;
        float r = rsqrtf(wredsum(d0 * d0 + d1 * d1) * 0.0078125f + 1e-5f);
        o[n].x = d0 * r * g2.x + bb2.x;
        o[n].y = d1 * r * g2.y + bb2.y;
    }
    float2 ac2[8];
#pragma unroll
    for (int n = 0; n < 8; ++n) {
        int i = i0 + (n < nn ? n : 0);
        ac2[n] = ld2(fused + (size_t)i * 128 + 2 * l);
    }
    mm8(o, ac2, fusW + (size_t)256 * 128, l);
    float2 fg2 = ld2(fg + 2 * l), fbe2 = ld2(fbe + 2 * l);
#pragma unroll
    for (int n = 0; n < 8; ++n) if (n < nn) {
        float v0 = ac2[n].x, v1 = ac2[n].y;
        float m = wredsum(v0 + v1) * 0.0078125f;
        float d0 = v0 - m, d1 = v1 - m;
        float r = rsqrtf(wredsum(d0 * d0 + d1 * d1) * 0.0078125f + 1e-5f);
        float2 res;
        res.x = d0 * r * fg2.x + fbe2.x;
        res.y = d1 * r * fg2.y + fbe2.y;
        st2(out + (size_t)(i0 + n) * 128 + 2 * l, res);
    }
}

extern "C" void kernel_launch(void* const* d_in, const int* in_sizes, int n_in, void* d_out,
                              int out_size, void* d_ws, size_t ws_size, hipStream_t stream) {
    (void)n_in; (void)out_size; (void)ws_size;
    const float* x = (const float*)d_in[0];
    const float* gat_Wq = (const float*)d_in[4];
    const float* gat_Wk = (const float*)d_in[5];
    const float* gat_Wv = (const float*)d_in[6];
    const float* gat_Wo = (const float*)d_in[7];
    const float* gat_bo = (const float*)d_in[8];
    const float* gat_g = (const float*)d_in[9];
    const float* gat_b = (const float*)d_in[10];
    const float* gcn_Wt = (const float*)d_in[11];
    const float* gcn_bt = (const float*)d_in[12];
    const float* gcn_mW1 = (const float*)d_in[13];
    const float* gcn_mb1 = (const float*)d_in[14];
    const float* gcn_mW2 = (const float*)d_in[15];
    const float* gcn_mb2 = (const float*)d_in[16];
    const float* gcn_aW1 = (const float*)d_in[17];
    const float* gcn_ab1 = (const float*)d_in[18];
    const float* gcn_aW2 = (const float*)d_in[19];
    const float* gcn_ab2 = (const float*)d_in[20];
    const float* gcn_Wo = (const float*)d_in[21];
    const float* gcn_bo = (const float*)d_in[22];
    const float* gcn_g = (const float*)d_in[23];
    const float* gcn_b = (const float*)d_in[24];
    const float* tmp_emb = (const float*)d_in[25];
    const float* tmp_W1 = (const float*)d_in[26];
    const float* tmp_b1 = (const float*)d_in[27];
    const float* tmp_W2 = (const float*)d_in[28];
    const float* tmp_b2 = (const float*)d_in[29];
    const float* tmp_Wo = (const float*)d_in[30];
    const float* tmp_bo = (const float*)d_in[31];
    const float* tmp_g = (const float*)d_in[32];
    const float* tmp_b = (const float*)d_in[33];
    const float* fus_W = (const float*)d_in[34];
    const float* fus_b = (const float*)d_in[35];
    const float* fus_g = (const float*)d_in[36];
    const float* fus_be = (const float*)d_in[37];

    int N = in_sizes[0] / 128;
    int E = in_sizes[1] / 2;

    // ---- workspace layout (floats) ----
    float* ws = (float*)d_ws;
    float* big = ws;                          // [0,384N): QKV during GAT phase
    float* fused = ws;                        // [0,128N): alias after QKV dead
    float* h_gcn = ws + (size_t)128 * N;      // [128N,256N)
    float* Pa = ws + (size_t)256 * N;         // [256N,384N): both branches
    float* Pb = ws + (size_t)384 * N;         // [384N,512N)
    float* agg = ws + (size_t)512 * N;        // [512N,640N): GAT agg / relu-sum s
    float* sm = ws + (size_t)640 * N;         // [640N,648N)
    u32* flags = (u32*)(ws + (size_t)648 * N);
    int* ei32 = (int*)(flags + 16);
    int* nt32 = ei32 + (size_t)2 * E;
    int* tp32 = nt32 + N;
    float* scores = (float*)(tp32 + N);       // E*8 floats
    int* offA = (int*)(scores + (size_t)8 * E);  // N+1
    int* cur = offA + (N + 1);                   // N (aliased as perm after col-sort)
    int* srow = cur + N;                         // E
    int* sedge = srow + E;                       // E
    int* tcnt = sedge + E;                       // 6
    int* toff = tcnt + 6;                        // 7
    int* tcur = toff + 7;                        // 6
    int* perm = cur;                             // alias: cur dead after col-scatter

    // ---- index canonicalization ----
    k_detect13<<<1, 64, 0, stream>>>((const u32*)d_in[1], (const u32*)d_in[2],
                                     (const u32*)d_in[3], flags);
    long long nEI = (long long)2 * E;
    k_cvt13<<<(int)((nEI + 255) / 256), 256, 0, stream>>>(d_in[1], ei32, nEI, flags, 0);
    k_cvt13<<<(N + 255) / 256, 256, 0, stream>>>(d_in[2], nt32, N, flags, 1);
    k_cvt13<<<(N + 255) / 256, 256, 0, stream>>>(d_in[3], tp32, N, flags, 2);

    int gE = (E + 255) / 256;
    int gN = (N + 255) / 256;
    int gB = (N + 31) / 32;   // 4 waves x 8 nodes per 256-thread block
    int gC = (N + 3) / 4;     // 4 cols (1 wave each) per 256-thread block
    int gE8 = (int)(((long long)E * 8 + 255) / 256);

    // ---- counting sort of edges by col ----
    kz_i<<<gN, 256, 0, stream>>>(cur, N);
    k_hist<<<gE, 256, 0, stream>>>(ei32, E, cur);
    k_scan<<<1, 1024, 0, stream>>>(cur, offA, N);
    kz_i<<<gN, 256, 0, stream>>>(cur, N);
    k_scatter<<<gE, 256, 0, stream>>>(ei32, E, offA, cur, srow, sedge);

    // ---- counting sort of nodes by type (perm aliases cur: col-scatter done) ----
    kz_i<<<1, 32, 0, stream>>>(tcnt, 19);
    k_thist<<<gN, 256, 0, stream>>>(nt32, N, tcnt);
    k_tscan<<<1, 64, 0, stream>>>(tcnt, toff);
    k_tscatter<<<gN, 256, 0, stream>>>(nt32, N, toff, tcur, perm);

    // ===== GAT branch =====
    kz13<<<(int)(((long long)8 * N + 255) / 256), 256, 0, stream>>>(sm, (long long)8 * N);
    k_qkv8<<<gB, 256, 0, stream>>>(x, gat_Wq, gat_Wk, gat_Wv, big, N);
    k_gat_smB<<<gE8, 256, 0, stream>>>(big, ei32, E, scores, sm);
    k_wvS2<<<gC, 256, 0, stream>>>(big, scores, sm, srow, sedge, offA, agg, N);
    k_ep_gatF8<<<gB, 256, 0, stream>>>(x, agg, gat_Wo, gat_bo, gat_g, gat_b,
                                       fus_W, fus_b, fused, N);   // QKV dead after this

    // ===== GCN branch =====
    k_hgcn8<<<gB, 256, 0, stream>>>(x, nt32, perm, gcn_Wt, gcn_bt, h_gcn, N);
    k_pre8<<<gB, 256, 0, stream>>>(h_gcn, nullptr, nullptr, gcn_mW1, gcn_mb1, Pa, Pb, N, 0);
    k_rsum2<<<gC, 256, 0, stream>>>(Pa, Pb, srow, offA, agg, N);
    k_ep_gcnF8<<<gB, 256, 0, stream>>>(x, h_gcn, agg, offA, gcn_mW2, gcn_mb2,
                                       gcn_aW1, gcn_ab1, gcn_aW2, gcn_ab2,
                                       gcn_Wo, gcn_bo, gcn_g, gcn_b, fus_W, fused, N);

    // ===== temporal branch =====
    k_pre8<<<gB, 256, 0, stream>>>(x, tmp_emb, tp32, tmp_W1, tmp_b1, Pa, Pb, N, 1);
    k_rsum2<<<gC, 256, 0, stream>>>(Pa, Pb, srow, offA, agg, N);
    k_ep_tmpF8<<<gB, 256, 0, stream>>>(x, tmp_emb, tp32, agg, offA, tmp_W2, tmp_b2,
                                       tmp_Wo, tmp_bo, tmp_g, tmp_b, fus_W, fused,
                                       fus_g, fus_be, (float*)d_out, N);
}